// Round 6
// baseline (152.141 us; speedup 1.0000x reference)
//
#include <hip/hip_runtime.h>
#include <hip/hip_bf16.h>
#include <math.h>

#define B_   64
#define S_   8
#define T_   8192
#define T3_  8166      // 8192 - 26
#define T3P  8168      // padded row stride
#define EPS_ 1e-8f
#define SWZ8(r) ((((r) >> 2) & 1) << 3)   // half-swizzle: XOR of the 16B-half by row bit 2

typedef __bf16 bf16x8 __attribute__((ext_vector_type(8)));
typedef float  f32x4  __attribute__((ext_vector_type(4)));

__device__ __forceinline__ unsigned short f2bf(float x) {
    __hip_bfloat16 h = __float2bfloat16(x);
    return *reinterpret_cast<unsigned short*>(&h);
}
__device__ __forceinline__ unsigned int pk2(float a, float b) {
    return (unsigned int)f2bf(a) | ((unsigned int)f2bf(b) << 16);
}
__device__ __forceinline__ bf16x8 as_bf(uint4 u) { return *reinterpret_cast<bf16x8*>(&u); }

// =========== K0: pack MFMA weight fragments to global (bf16) ===========
// wfE (2560): [W1e(cin8) | W2a | W2b | W3a | W3b]  (eeg stack, unchanged)
// wfS (2560): [W1h(Hankel k<3) | W2a | W2b | W3a | W3b]  (stim stack)
__global__ __launch_bounds__(256) void k_pack(
        const float* __restrict__ w_e1, const float* __restrict__ w_e2, const float* __restrict__ w_e3,
        const float* __restrict__ w_s1, const float* __restrict__ w_s2, const float* __restrict__ w_s3,
        unsigned short* __restrict__ wfE, unsigned short* __restrict__ wfS) {
    int tid = threadIdx.x;
    for (int idx = tid; idx < 2560; idx += 256) {
        int arr = idx >> 9, e = idx & 511;
        int m = e >> 5, k5 = e & 31;
        float v = 0.f;
        if (arr == 0)      { int tap = k5 >> 3, ci = k5 & 7; if (tap < 3) v = w_e1[(m * 8 + ci) * 3 + tap]; }
        else if (arr == 1) { int tap = k5 >> 4, ci = k5 & 15; v = w_e2[(m * 16 + ci) * 3 + tap]; }
        else if (arr == 2) { if (k5 < 16) v = w_e2[(m * 16 + k5) * 3 + 2]; }
        else if (arr == 3) { int tap = k5 >> 4, ci = k5 & 15; v = w_e3[(m * 16 + ci) * 3 + tap]; }
        else               { if (k5 < 16) v = w_e3[(m * 16 + k5) * 3 + 2]; }
        wfE[idx] = f2bf(v);
    }
    for (int idx = tid; idx < 2560; idx += 256) {
        int arr = idx >> 9, e = idx & 511;
        int m = e >> 5, k5 = e & 31;
        float v = 0.f;
        if (arr == 0)      { if (k5 < 3) v = w_s1[m * 3 + k5]; }
        else if (arr == 1) { int tap = k5 >> 4, ci = k5 & 15; v = w_s2[(m * 16 + ci) * 3 + tap]; }
        else if (arr == 2) { if (k5 < 16) v = w_s2[(m * 16 + k5) * 3 + 2]; }
        else if (arr == 3) { int tap = k5 >> 4, ci = k5 & 15; v = w_s3[(m * 16 + ci) * 3 + tap]; }
        else               { if (k5 < 16) v = w_s3[(m * 16 + k5) * 3 + 2]; }
        wfS[idx] = f2bf(v);
    }
}

// =========== KA: streaming 1x1 conv 64->8, [B,T,64] f32 -> [B,T,8] bf16 ===========
__global__ __launch_bounds__(256) void k_eeg1x1(const float* __restrict__ eeg,
                                                const float* __restrict__ w,
                                                const float* __restrict__ bias,
                                                unsigned short* __restrict__ x0b) {
    __shared__ float ws[512];
    __shared__ float bs[8];
    int tid = threadIdx.x;
    ws[tid]       = w[tid];
    ws[tid + 256] = w[tid + 256];
    if (tid < 8) bs[tid] = bias[tid];
    __syncthreads();

    int gt = blockIdx.x * 256 + tid;
    const float* ep = eeg + (size_t)gt * 64;

    float acc[8];
#pragma unroll
    for (int c = 0; c < 8; ++c) acc[c] = bs[c];
#pragma unroll
    for (int i = 0; i < 64; i += 4) {
        float4 v = *(const float4*)(ep + i);
#pragma unroll
        for (int c = 0; c < 8; ++c) {
            const float* wp = ws + c * 64 + i;
            acc[c] += v.x * wp[0] + v.y * wp[1] + v.z * wp[2] + v.w * wp[3];
        }
    }
    uint4 p = { pk2(acc[0], acc[1]), pk2(acc[2], acc[3]),
                pk2(acc[4], acc[5]), pk2(acc[6], acc[7]) };
    *(uint4*)(x0b + (size_t)gt * 8) = p;
}

// =========== KB: eeg dilated stack via MFMA, chunk=256 (R5-verified, unchanged) ===========
__global__ __launch_bounds__(256) void k_estack(const unsigned short* __restrict__ x0b,
        const float* __restrict__ b1, const float* __restrict__ b2, const float* __restrict__ b3,
        const unsigned short* __restrict__ wfE,
        unsigned short* __restrict__ x3b, float* __restrict__ nxp) {
    __shared__ __align__(16) unsigned char smem[24064];
    unsigned short* x0T = (unsigned short*)smem;
    unsigned short* i1  = (unsigned short*)(smem + 4864);
    unsigned short* i2  = (unsigned short*)(smem + 14592);
    float*          wred= (float*)(smem + 23808);
    unsigned short* st3 = (unsigned short*)smem;

    int tid = threadIdx.x;
    int chunk = blockIdx.x, b = blockIdx.y;
    int wv = tid >> 6, lane = tid & 63, lm = lane & 15, lg = lane >> 4;

    int c0 = chunk * 256;
    int Lv = min(256, T3_ - c0);
    int n_in = Lv + 26, n1 = Lv + 24;
    int nub1 = (n1 + 15) >> 4;

    {
        const unsigned short* src = x0b + ((size_t)b * T_ + c0) * 8;
        uint4 z = {0, 0, 0, 0};
        for (int r = tid; r < 304; r += 256) {
            uint4 v = (r < n_in) ? *(const uint4*)(src + r * 8) : z;
            *(uint4*)(x0T + r * 8) = v;
        }
    }
    {
        int z1 = nub1 * 16;
        for (int idx = tid; idx < (304 - z1) * 8; idx += 256)
            ((unsigned int*)(i1 + z1 * 16))[idx] = 0;
    }
    __syncthreads();

    const bf16x8 W1f = *(const bf16x8*)(wfE +         lm * 32 + 8 * lg);
    const bf16x8 W2a = *(const bf16x8*)(wfE + 512  +  lm * 32 + 8 * lg);
    const bf16x8 W2b = *(const bf16x8*)(wfE + 1024 +  lm * 32 + 8 * lg);
    const bf16x8 W3a = *(const bf16x8*)(wfE + 1536 +  lm * 32 + 8 * lg);
    const bf16x8 W3b = *(const bf16x8*)(wfE + 2048 +  lm * 32 + 8 * lg);
    f32x4 c1v, c2v, c3v;
#pragma unroll
    for (int r = 0; r < 4; ++r) {
        int m = 4 * lg + r;
        c1v[r] = b1[m]; c2v[r] = b2[m]; c3v[r] = b3[m];
    }

    for (int ub = wv; ub < nub1; ub += 4) {
        int u = ub * 16 + lm;
        bf16x8 Ba = *(const bf16x8*)(x0T + (u + lg) * 8);
        f32x4 acc = __builtin_amdgcn_mfma_f32_16x16x32_bf16(W1f, Ba, c1v, 0, 0, 0);
        uint2 pq = { pk2(fmaxf(acc[0], 0.f), fmaxf(acc[1], 0.f)),
                     pk2(fmaxf(acc[2], 0.f), fmaxf(acc[3], 0.f)) };
        *(uint2*)(i1 + u * 16 + (((lg >> 1) << 3) ^ SWZ8(u)) + (lg & 1) * 4) = pq;
    }
    __syncthreads();

    for (int ub = wv; ub < 18; ub += 4) {
        int u = ub * 16 + lm;
        int t3 = 3 * (lg >> 1);
        int ra = u + t3, rb = u + 6 + t3;
        bf16x8 Ba = *(const bf16x8*)(i1 + ra * 16 + ((((lg & 1) << 3)) ^ SWZ8(ra)));
        bf16x8 Bb = *(const bf16x8*)(i1 + rb * 16 + ((((lg & 1) << 3)) ^ SWZ8(rb)));
        f32x4 acc = c2v;
        acc = __builtin_amdgcn_mfma_f32_16x16x32_bf16(W2a, Ba, acc, 0, 0, 0);
        acc = __builtin_amdgcn_mfma_f32_16x16x32_bf16(W2b, Bb, acc, 0, 0, 0);
        uint2 pq = { pk2(fmaxf(acc[0], 0.f), fmaxf(acc[1], 0.f)),
                     pk2(fmaxf(acc[2], 0.f), fmaxf(acc[3], 0.f)) };
        *(uint2*)(i2 + u * 16 + (((lg >> 1) << 3) ^ SWZ8(u)) + (lg & 1) * 4) = pq;
    }
    __syncthreads();

    float nst[4] = {0.f, 0.f, 0.f, 0.f};
    for (int ub = wv; ub < 16; ub += 4) {
        int u = ub * 16 + lm;
        int t9 = 9 * (lg >> 1);
        int ra = u + t9, rb = u + 18 + t9;
        bf16x8 Ba = *(const bf16x8*)(i2 + ra * 16 + ((((lg & 1) << 3)) ^ SWZ8(ra)));
        bf16x8 Bb = *(const bf16x8*)(i2 + rb * 16 + ((((lg & 1) << 3)) ^ SWZ8(rb)));
        f32x4 acc = c3v;
        acc = __builtin_amdgcn_mfma_f32_16x16x32_bf16(W3a, Ba, acc, 0, 0, 0);
        acc = __builtin_amdgcn_mfma_f32_16x16x32_bf16(W3b, Bb, acc, 0, 0, 0);
        bool ok = u < Lv;
#pragma unroll
        for (int r = 0; r < 4; ++r) {
            float v = ok ? fmaxf(acc[r], 0.f) : 0.f;
            nst[r] += v * v;
            st3[(4 * lg + r) * 264 + u] = f2bf(v);
        }
    }
#pragma unroll
    for (int r = 0; r < 4; ++r) {
        float t = nst[r];
        t += __shfl_xor(t, 1); t += __shfl_xor(t, 2);
        t += __shfl_xor(t, 4); t += __shfl_xor(t, 8);
        nst[r] = t;
    }
    if (lm == 0) {
#pragma unroll
        for (int r = 0; r < 4; ++r) wred[wv * 16 + 4 * lg + r] = nst[r];
    }
    __syncthreads();

    if (tid < 16) {
        float s = wred[tid] + wred[16 + tid] + wred[32 + tid] + wred[48 + tid];
        nxp[((size_t)b * 16 + tid) * 32 + chunk] = s;
    }
    {
        unsigned short* dst = x3b + (size_t)(b * 16) * T3P + c0;
        for (int idx = tid; idx < 16 * 32; idx += 256) {
            int co = idx >> 5, off = (idx & 31) * 8;
            if (off + 8 <= Lv)
                *(uint4*)(dst + (size_t)co * T3P + off) = *(const uint4*)(st3 + co * 264 + off);
            else
                for (int k = off; k < Lv; ++k) dst[(size_t)co * T3P + k] = st3[co * 264 + k];
        }
        if (chunk == 31 && tid < 16)
            *(unsigned int*)(x3b + (size_t)(b * 16 + tid) * T3P + T3_) = 0;
    }
}

// =========== K4: stim stack, all-MFMA (Hankel conv1, transposed conv3), chunk=512 ===========
// grid (512 bs, 4 G): each block does 4 chunks of 512. LDS 35,328B -> 4 blocks/CU.
__global__ __launch_bounds__(256, 4) void k_stim(const float* __restrict__ stim,
                                              const float* __restrict__ b1,
                                              const float* __restrict__ b2,
                                              const float* __restrict__ b3,
                                              const unsigned short* __restrict__ wfS,
                                              const unsigned short* __restrict__ x3b,
                                              float* __restrict__ dotp, float* __restrict__ nstp) {
    // LDS: i1 u16[560][16] @0 (17920) ; i2 u16[544][16] @17920 (17408) -> 35328
    // s3 u16[16][520] aliases i1 (dead after conv2)
    __shared__ __align__(16) unsigned char smem[35328];
    unsigned short* i1 = (unsigned short*)smem;
    unsigned short* i2 = (unsigned short*)(smem + 17920);
    unsigned short* s3 = i1;

    int tid  = threadIdx.x;
    int bs   = blockIdx.x;
    int G    = blockIdx.y;
    int wv   = tid >> 6;
    int lane = tid & 63;
    int lm   = lane & 15;
    int lg   = lane >> 4;

    const bf16x8 W1f = *(const bf16x8*)(wfS +         lm * 32 + 8 * lg);
    const bf16x8 W2a = *(const bf16x8*)(wfS + 512  +  lm * 32 + 8 * lg);
    const bf16x8 W2b = *(const bf16x8*)(wfS + 1024 +  lm * 32 + 8 * lg);
    const bf16x8 W3a = *(const bf16x8*)(wfS + 1536 +  lm * 32 + 8 * lg);
    const bf16x8 W3b = *(const bf16x8*)(wfS + 2048 +  lm * 32 + 8 * lg);
    f32x4 c1v, c2v, c3v;
#pragma unroll
    for (int r = 0; r < 4; ++r) {
        c1v[r] = b1[4 * lg + r];
        c2v[r] = b2[4 * lg + r];
        c3v[r] = b3[lm];          // transposed conv3: C col = channel = lm
    }

    const float* seq = stim + (size_t)bs * T_;
    int b16 = (bs >> 3) * 16;

    f32x4 dacc;
#pragma unroll
    for (int r = 0; r < 4; ++r) dacc[r] = 0.f;
    float nstc = 0.f;

    for (int cc = 0; cc < 4; ++cc) {
        int c0 = (G * 4 + cc) * 512;
        int Lv = min(512, T3_ - c0);
        int n1 = Lv + 24;

        __syncthreads();   // prev chunk's dot (reads s3=i1) done before overwrite

        // zero i1 tail rows [n1, 560)
        for (int z = tid; z < (560 - n1) * 8; z += 256)
            ((unsigned int*)(i1 + n1 * 16))[z] = 0;

        // conv1 (MFMA, Hankel B from global): only lg==0 lanes carry data (k<3)
        for (int ub = wv; ub < 34; ub += 4) {
            int t = ub * 16 + lm;
            bool vld = t < n1;
            unsigned int wa = 0u, wb = 0u;
            if (lg == 0 && vld) {
                const float* sp = seq + c0 + t;
                float s0 = sp[0], s1 = sp[1], s2 = sp[2];
                wa = pk2(s0, s1);
                wb = pk2(s2, 0.f);
            }
            uint4 bfv = { wa, wb, 0u, 0u };
            f32x4 acc = __builtin_amdgcn_mfma_f32_16x16x32_bf16(W1f, as_bf(bfv), c1v, 0, 0, 0);
            if (vld) {
                uint2 pq = { pk2(fmaxf(acc[0], 0.f), fmaxf(acc[1], 0.f)),
                             pk2(fmaxf(acc[2], 0.f), fmaxf(acc[3], 0.f)) };
                *(uint2*)(i1 + t * 16 + (((lg >> 1) << 3) ^ SWZ8(t)) + (lg & 1) * 4) = pq;
            }
        }
        __syncthreads();

        // conv2 d=3 (fixed 34 ub -> all 544 i2 rows written)
        for (int ub = wv; ub < 34; ub += 4) {
            int u = ub * 16 + lm;
            int t3 = 3 * (lg >> 1);
            int ra = u + t3, rb = u + 6 + t3;
            bf16x8 Ba = *(const bf16x8*)(i1 + ra * 16 + (((lg & 1) << 3) ^ SWZ8(ra)));
            bf16x8 Bb = *(const bf16x8*)(i1 + rb * 16 + (((lg & 1) << 3) ^ SWZ8(rb)));
            f32x4 acc = c2v;
            acc = __builtin_amdgcn_mfma_f32_16x16x32_bf16(W2a, Ba, acc, 0, 0, 0);
            acc = __builtin_amdgcn_mfma_f32_16x16x32_bf16(W2b, Bb, acc, 0, 0, 0);
            uint2 pq = { pk2(fmaxf(acc[0], 0.f), fmaxf(acc[1], 0.f)),
                         pk2(fmaxf(acc[2], 0.f), fmaxf(acc[3], 0.f)) };
            *(uint2*)(i2 + u * 16 + (((lg >> 1) << 3) ^ SWZ8(u)) + (lg & 1) * 4) = pq;
        }
        __syncthreads();

        // conv3 d=9 TRANSPOSED: mfma(A=i2 rows, B=W3) -> C col=ch, row=u -> b64 writes
        for (int ub = wv; ub < 32; ub += 4) {
            int u0 = ub * 16;
            int ra = u0 + lm + 9 * (lg >> 1);
            int rb = ra + 18;
            bf16x8 Aa = *(const bf16x8*)(i2 + ra * 16 + (((lg & 1) << 3) ^ SWZ8(ra)));
            bf16x8 Ab = *(const bf16x8*)(i2 + rb * 16 + (((lg & 1) << 3) ^ SWZ8(rb)));
            f32x4 acc = c3v;
            acc = __builtin_amdgcn_mfma_f32_16x16x32_bf16(Aa, W3a, acc, 0, 0, 0);
            acc = __builtin_amdgcn_mfma_f32_16x16x32_bf16(Ab, W3b, acc, 0, 0, 0);
            int u4 = u0 + 4 * lg;
            float v[4];
#pragma unroll
            for (int r = 0; r < 4; ++r) {
                float x = ((u4 + r) < Lv) ? fmaxf(acc[r], 0.f) : 0.f;
                v[r] = x;
                nstc += x * x;
            }
            uint2 pq = { pk2(v[0], v[1]), pk2(v[2], v[3]) };
            *(uint2*)(s3 + lm * 520 + u4) = pq;
        }
        __syncthreads();

        // dot (MFMA): dacc[i][j] += st3 . x3^T, waves split K (t)
#pragma unroll
        for (int kk = 0; kk < 4; ++kk) {
            int tl = wv * 128 + kk * 32 + lg * 8;
            bf16x8 Af = *(const bf16x8*)(s3 + lm * 520 + tl);
            int tg = c0 + tl;
            int tc = (tg > 8160) ? 0 : tg;      // clamped lanes have A==0
            bf16x8 Bf = *(const bf16x8*)(x3b + (size_t)(b16 + lm) * T3P + tc);
            dacc = __builtin_amdgcn_mfma_f32_16x16x32_bf16(Af, Bf, dacc, 0, 0, 0);
        }
    }

    // nst: lane holds channel lm partial; reduce over lg (lanes +16, +32)
    nstc += __shfl_xor(nstc, 16);
    nstc += __shfl_xor(nstc, 32);
    int ob = (bs * 4 + G) * 4 + wv;
    *(f32x4*)(dotp + (size_t)ob * 256 + lane * 4) = dacc;
    if (lg == 0) nstp[(size_t)ob * 16 + lm] = nstc;
}

// =========== K5: reduce partials, cosine, linear head ===========
__global__ __launch_bounds__(256) void k_head(const float* __restrict__ dotp,
                                              const float* __restrict__ nstp,
                                              const float* __restrict__ nxp,
                                              const float* __restrict__ wlin,
                                              const float* __restrict__ blin,
                                              float* __restrict__ out) {
    int bs = blockIdx.x, tid = threadIdx.x;
    int b = bs >> 3;
    __shared__ float nxv[16];
    if (tid < 16) {
        float s = 0.f;
#pragma unroll
        for (int ch = 0; ch < 32; ++ch) s += nxp[((size_t)b * 16 + tid) * 32 + ch];
        nxv[tid] = fmaxf(sqrtf(s), EPS_);
    }
    __syncthreads();
    int i = 4 * (tid >> 6) + (tid & 3);
    int j = (tid >> 2) & 15;
    float dot = 0.f, ss = 0.f;
#pragma unroll
    for (int gw = 0; gw < 16; ++gw) {
        dot += dotp[(size_t)(bs * 16 + gw) * 256 + tid];
        ss  += nstp[(size_t)(bs * 16 + gw) * 16 + i];
    }
    float nstv = fmaxf(sqrtf(ss), EPS_);
    float val = dot / (nstv * nxv[j]) * wlin[i * 16 + j];
#pragma unroll
    for (int m = 32; m > 0; m >>= 1) val += __shfl_down(val, m, 64);
    __shared__ float rd[4];
    if ((tid & 63) == 0) rd[tid >> 6] = val;
    __syncthreads();
    if (tid == 0) out[bs] = rd[0] + rd[1] + rd[2] + rd[3] + blin[0];
}

extern "C" void kernel_launch(void* const* d_in, const int* in_sizes, int n_in,
                              void* d_out, int out_size, void* d_ws, size_t ws_size,
                              hipStream_t stream) {
    const float* eeg   = (const float*)d_in[0];
    const float* stim  = (const float*)d_in[1];
    const float* w_eeg = (const float*)d_in[2];
    const float* b_eeg = (const float*)d_in[3];
    const float* w_e1  = (const float*)d_in[4];
    const float* b_e1  = (const float*)d_in[5];
    const float* w_e2  = (const float*)d_in[6];
    const float* b_e2  = (const float*)d_in[7];
    const float* w_e3  = (const float*)d_in[8];
    const float* b_e3  = (const float*)d_in[9];
    const float* w_s1  = (const float*)d_in[10];
    const float* b_s1  = (const float*)d_in[11];
    const float* w_s2  = (const float*)d_in[12];
    const float* b_s2  = (const float*)d_in[13];
    const float* w_s3  = (const float*)d_in[14];
    const float* b_s3  = (const float*)d_in[15];
    const float* w_lin = (const float*)d_in[16];
    const float* b_lin = (const float*)d_in[17];

    unsigned char* ws = (unsigned char*)d_ws;
    unsigned short* x3b  = (unsigned short*)ws;                 // 16,728,064 B
    float*          nxp  = (float*)(ws + 16728064);             // 131,072 B
    float*          dotp = (float*)(ws + 16859136);             // 8,388,608 B
    float*          nstp = (float*)(ws + 25247744);             // 524,288 B
    unsigned short* x0b  = (unsigned short*)(ws + 25772032);    // 8,388,608 B
    unsigned short* wfE  = (unsigned short*)(ws + 34160640);    // 5,120 B
    unsigned short* wfS  = (unsigned short*)(ws + 34165760);    // 5,120 B
    float*          out  = (float*)d_out;

    k_pack<<<1, 256, 0, stream>>>(w_e1, w_e2, w_e3, w_s1, w_s2, w_s3, wfE, wfS);
    k_eeg1x1<<<(B_ * T_) / 256, 256, 0, stream>>>(eeg, w_eeg, b_eeg, x0b);
    k_estack<<<dim3(32, B_), 256, 0, stream>>>(x0b, b_e1, b_e2, b_e3, wfE, x3b, nxp);
    k_stim<<<dim3(B_ * S_, 4), 256, 0, stream>>>(stim, b_s1, b_s2, b_s3,
                                                 wfS, x3b, dotp, nstp);
    k_head<<<B_ * S_, 256, 0, stream>>>(dotp, nstp, nxp, w_lin, b_lin, out);
}

// Round 8
// 126.012 us; speedup vs baseline: 1.2074x; 1.2074x over previous
//
#include <hip/hip_runtime.h>
#include <hip/hip_bf16.h>
#include <math.h>

#define B_   64
#define S_   8
#define T_   8192
#define T3_  8166      // 8192 - 26
#define T3P  8168      // padded row stride
#define EPS_ 1e-8f
#define SWZ8(r) ((((r) >> 2) & 1) << 3)   // half-swizzle: XOR of the 16B-half by row bit 2

typedef __bf16 bf16x8 __attribute__((ext_vector_type(8)));
typedef float  f32x4  __attribute__((ext_vector_type(4)));

__device__ __forceinline__ unsigned short f2bf(float x) {
    __hip_bfloat16 h = __float2bfloat16(x);
    return *reinterpret_cast<unsigned short*>(&h);
}
__device__ __forceinline__ unsigned int pk2(float a, float b) {
    return (unsigned int)f2bf(a) | ((unsigned int)f2bf(b) << 16);
}
__device__ __forceinline__ bf16x8 as_bf(uint4 u) { return *reinterpret_cast<bf16x8*>(&u); }

// =========== K0: pack MFMA weight fragments to global (bf16) ===========
__global__ __launch_bounds__(256) void k_pack(
        const float* __restrict__ w_e1, const float* __restrict__ w_e2, const float* __restrict__ w_e3,
        const float* __restrict__ w_s1, const float* __restrict__ w_s2, const float* __restrict__ w_s3,
        unsigned short* __restrict__ wfE, unsigned short* __restrict__ wfS) {
    int tid = threadIdx.x;
    for (int idx = tid; idx < 2560; idx += 256) {
        int arr = idx >> 9, e = idx & 511;
        int m = e >> 5, k5 = e & 31;
        float v = 0.f;
        if (arr == 0)      { int tap = k5 >> 3, ci = k5 & 7; if (tap < 3) v = w_e1[(m * 8 + ci) * 3 + tap]; }
        else if (arr == 1) { int tap = k5 >> 4, ci = k5 & 15; v = w_e2[(m * 16 + ci) * 3 + tap]; }
        else if (arr == 2) { if (k5 < 16) v = w_e2[(m * 16 + k5) * 3 + 2]; }
        else if (arr == 3) { int tap = k5 >> 4, ci = k5 & 15; v = w_e3[(m * 16 + ci) * 3 + tap]; }
        else               { if (k5 < 16) v = w_e3[(m * 16 + k5) * 3 + 2]; }
        wfE[idx] = f2bf(v);
    }
    for (int idx = tid; idx < 2560; idx += 256) {
        int arr = idx >> 9, e = idx & 511;
        int m = e >> 5, k5 = e & 31;
        float v = 0.f;
        if (arr == 0)      { if (k5 < 3) v = w_s1[m * 3 + k5]; }
        else if (arr == 1) { int tap = k5 >> 4, ci = k5 & 15; v = w_s2[(m * 16 + ci) * 3 + tap]; }
        else if (arr == 2) { if (k5 < 16) v = w_s2[(m * 16 + k5) * 3 + 2]; }
        else if (arr == 3) { int tap = k5 >> 4, ci = k5 & 15; v = w_s3[(m * 16 + ci) * 3 + tap]; }
        else               { if (k5 < 16) v = w_s3[(m * 16 + k5) * 3 + 2]; }
        wfS[idx] = f2bf(v);
    }
}

// =========== KA: streaming 1x1 conv 64->8, [B,T,64] f32 -> [B,T,8] bf16 ===========
__global__ __launch_bounds__(256) void k_eeg1x1(const float* __restrict__ eeg,
                                                const float* __restrict__ w,
                                                const float* __restrict__ bias,
                                                unsigned short* __restrict__ x0b) {
    __shared__ float ws[512];
    __shared__ float bs[8];
    int tid = threadIdx.x;
    ws[tid]       = w[tid];
    ws[tid + 256] = w[tid + 256];
    if (tid < 8) bs[tid] = bias[tid];
    __syncthreads();

    int gt = blockIdx.x * 256 + tid;
    const float* ep = eeg + (size_t)gt * 64;

    float acc[8];
#pragma unroll
    for (int c = 0; c < 8; ++c) acc[c] = bs[c];
#pragma unroll
    for (int i = 0; i < 64; i += 4) {
        float4 v = *(const float4*)(ep + i);
#pragma unroll
        for (int c = 0; c < 8; ++c) {
            const float* wp = ws + c * 64 + i;
            acc[c] += v.x * wp[0] + v.y * wp[1] + v.z * wp[2] + v.w * wp[3];
        }
    }
    uint4 p = { pk2(acc[0], acc[1]), pk2(acc[2], acc[3]),
                pk2(acc[4], acc[5]), pk2(acc[6], acc[7]) };
    *(uint4*)(x0b + (size_t)gt * 8) = p;
}

// =========== KB: eeg dilated stack via MFMA, chunk=256 (R5-verified, unchanged) ===========
__global__ __launch_bounds__(256) void k_estack(const unsigned short* __restrict__ x0b,
        const float* __restrict__ b1, const float* __restrict__ b2, const float* __restrict__ b3,
        const unsigned short* __restrict__ wfE,
        unsigned short* __restrict__ x3b, float* __restrict__ nxp) {
    __shared__ __align__(16) unsigned char smem[24064];
    unsigned short* x0T = (unsigned short*)smem;
    unsigned short* i1  = (unsigned short*)(smem + 4864);
    unsigned short* i2  = (unsigned short*)(smem + 14592);
    float*          wred= (float*)(smem + 23808);
    unsigned short* st3 = (unsigned short*)smem;

    int tid = threadIdx.x;
    int chunk = blockIdx.x, b = blockIdx.y;
    int wv = tid >> 6, lane = tid & 63, lm = lane & 15, lg = lane >> 4;

    int c0 = chunk * 256;
    int Lv = min(256, T3_ - c0);
    int n_in = Lv + 26, n1 = Lv + 24;
    int nub1 = (n1 + 15) >> 4;

    {
        const unsigned short* src = x0b + ((size_t)b * T_ + c0) * 8;
        uint4 z = {0, 0, 0, 0};
        for (int r = tid; r < 304; r += 256) {
            uint4 v = (r < n_in) ? *(const uint4*)(src + r * 8) : z;
            *(uint4*)(x0T + r * 8) = v;
        }
    }
    {
        int z1 = nub1 * 16;
        for (int idx = tid; idx < (304 - z1) * 8; idx += 256)
            ((unsigned int*)(i1 + z1 * 16))[idx] = 0;
    }
    __syncthreads();

    const bf16x8 W1f = *(const bf16x8*)(wfE +         lm * 32 + 8 * lg);
    const bf16x8 W2a = *(const bf16x8*)(wfE + 512  +  lm * 32 + 8 * lg);
    const bf16x8 W2b = *(const bf16x8*)(wfE + 1024 +  lm * 32 + 8 * lg);
    const bf16x8 W3a = *(const bf16x8*)(wfE + 1536 +  lm * 32 + 8 * lg);
    const bf16x8 W3b = *(const bf16x8*)(wfE + 2048 +  lm * 32 + 8 * lg);
    f32x4 c1v, c2v, c3v;
#pragma unroll
    for (int r = 0; r < 4; ++r) {
        int m = 4 * lg + r;
        c1v[r] = b1[m]; c2v[r] = b2[m]; c3v[r] = b3[m];
    }

    for (int ub = wv; ub < nub1; ub += 4) {
        int u = ub * 16 + lm;
        bf16x8 Ba = *(const bf16x8*)(x0T + (u + lg) * 8);
        f32x4 acc = __builtin_amdgcn_mfma_f32_16x16x32_bf16(W1f, Ba, c1v, 0, 0, 0);
        uint2 pq = { pk2(fmaxf(acc[0], 0.f), fmaxf(acc[1], 0.f)),
                     pk2(fmaxf(acc[2], 0.f), fmaxf(acc[3], 0.f)) };
        *(uint2*)(i1 + u * 16 + (((lg >> 1) << 3) ^ SWZ8(u)) + (lg & 1) * 4) = pq;
    }
    __syncthreads();

    for (int ub = wv; ub < 18; ub += 4) {
        int u = ub * 16 + lm;
        int t3 = 3 * (lg >> 1);
        int ra = u + t3, rb = u + 6 + t3;
        bf16x8 Ba = *(const bf16x8*)(i1 + ra * 16 + ((((lg & 1) << 3)) ^ SWZ8(ra)));
        bf16x8 Bb = *(const bf16x8*)(i1 + rb * 16 + ((((lg & 1) << 3)) ^ SWZ8(rb)));
        f32x4 acc = c2v;
        acc = __builtin_amdgcn_mfma_f32_16x16x32_bf16(W2a, Ba, acc, 0, 0, 0);
        acc = __builtin_amdgcn_mfma_f32_16x16x32_bf16(W2b, Bb, acc, 0, 0, 0);
        uint2 pq = { pk2(fmaxf(acc[0], 0.f), fmaxf(acc[1], 0.f)),
                     pk2(fmaxf(acc[2], 0.f), fmaxf(acc[3], 0.f)) };
        *(uint2*)(i2 + u * 16 + (((lg >> 1) << 3) ^ SWZ8(u)) + (lg & 1) * 4) = pq;
    }
    __syncthreads();

    float nst[4] = {0.f, 0.f, 0.f, 0.f};
    for (int ub = wv; ub < 16; ub += 4) {
        int u = ub * 16 + lm;
        int t9 = 9 * (lg >> 1);
        int ra = u + t9, rb = u + 18 + t9;
        bf16x8 Ba = *(const bf16x8*)(i2 + ra * 16 + ((((lg & 1) << 3)) ^ SWZ8(ra)));
        bf16x8 Bb = *(const bf16x8*)(i2 + rb * 16 + ((((lg & 1) << 3)) ^ SWZ8(rb)));
        f32x4 acc = c3v;
        acc = __builtin_amdgcn_mfma_f32_16x16x32_bf16(W3a, Ba, acc, 0, 0, 0);
        acc = __builtin_amdgcn_mfma_f32_16x16x32_bf16(W3b, Bb, acc, 0, 0, 0);
        bool ok = u < Lv;
#pragma unroll
        for (int r = 0; r < 4; ++r) {
            float v = ok ? fmaxf(acc[r], 0.f) : 0.f;
            nst[r] += v * v;
            st3[(4 * lg + r) * 264 + u] = f2bf(v);
        }
    }
#pragma unroll
    for (int r = 0; r < 4; ++r) {
        float t = nst[r];
        t += __shfl_xor(t, 1); t += __shfl_xor(t, 2);
        t += __shfl_xor(t, 4); t += __shfl_xor(t, 8);
        nst[r] = t;
    }
    if (lm == 0) {
#pragma unroll
        for (int r = 0; r < 4; ++r) wred[wv * 16 + 4 * lg + r] = nst[r];
    }
    __syncthreads();

    if (tid < 16) {
        float s = wred[tid] + wred[16 + tid] + wred[32 + tid] + wred[48 + tid];
        nxp[((size_t)b * 16 + tid) * 32 + chunk] = s;
    }
    {
        unsigned short* dst = x3b + (size_t)(b * 16) * T3P + c0;
        for (int idx = tid; idx < 16 * 32; idx += 256) {
            int co = idx >> 5, off = (idx & 31) * 8;
            if (off + 8 <= Lv)
                *(uint4*)(dst + (size_t)co * T3P + off) = *(const uint4*)(st3 + co * 264 + off);
            else
                for (int k = off; k < Lv; ++k) dst[(size_t)co * T3P + k] = st3[co * 264 + k];
        }
        if (chunk == 31 && tid < 16)
            *(unsigned int*)(x3b + (size_t)(b * 16 + tid) * T3P + T3_) = 0;
    }
}

// =========== K4: stim stack, unrolled const-offset MFMA, chunk=512, prefetched ===========
// grid (512 bs, 4 G): each block does 4 chunks of 512. LDS 37,520B -> 4 blocks/CU.
__global__ __launch_bounds__(256, 4) void k_stim(const float* __restrict__ stim,
                                              const float* __restrict__ b1,
                                              const float* __restrict__ b2,
                                              const float* __restrict__ b3,
                                              const unsigned short* __restrict__ wfS,
                                              const unsigned short* __restrict__ x3b,
                                              float* __restrict__ dotp, float* __restrict__ nstp) {
    // LDS: sinb f32[548] @0 (2192) ; i1 u16[560][16] @2192 (17920) ; i2 u16[544][16] @20112 (17408)
    // s3 u16[16][520] aliases i1 (dead after conv2)
    __shared__ __align__(16) unsigned char smem[37520];
    float*          sinb = (float*)smem;
    unsigned short* i1   = (unsigned short*)(smem + 2192);
    unsigned short* i2   = (unsigned short*)(smem + 20112);
    unsigned short* s3   = i1;

    int tid  = threadIdx.x;
    int bs   = blockIdx.x;
    int G    = blockIdx.y;
    int wv   = tid >> 6;
    int lane = tid & 63;
    int lm   = lane & 15;
    int lg   = lane >> 4;

    const bf16x8 W1f = *(const bf16x8*)(wfS +         lm * 32 + 8 * lg);
    const bf16x8 W2a = *(const bf16x8*)(wfS + 512  +  lm * 32 + 8 * lg);
    const bf16x8 W2b = *(const bf16x8*)(wfS + 1024 +  lm * 32 + 8 * lg);
    const bf16x8 W3a = *(const bf16x8*)(wfS + 1536 +  lm * 32 + 8 * lg);
    const bf16x8 W3b = *(const bf16x8*)(wfS + 2048 +  lm * 32 + 8 * lg);
    f32x4 c1v, c2v, c3v;
#pragma unroll
    for (int r = 0; r < 4; ++r) {
        c1v[r] = b1[4 * lg + r];
        c2v[r] = b2[4 * lg + r];
        c3v[r] = b3[lm];          // transposed conv3: C col = channel = lm
    }

    const float* seq = stim + (size_t)bs * T_;
    int b16 = (bs >> 3) * 16;

    // ---- hoisted per-lane swizzled bases (SWZ8 invariant under +64-row steps) ----
    int t0   = wv * 16 + lm;
    const float*    p1  = sinb + t0;                                             // conv1 reads
    unsigned short* pw1 = i1 + t0 * 16 + ((((lg >> 1) << 3) ^ SWZ8(t0)) + (lg & 1) * 4);
    int ra2 = t0 + 3 * (lg >> 1);
    const unsigned short* pa2 = i1 + ra2 * 16 + (((lg & 1) << 3) ^ SWZ8(ra2));
    const unsigned short* pb2 = i1 + (ra2 + 6) * 16 + (((lg & 1) << 3) ^ SWZ8(ra2 + 6));
    unsigned short* pw2 = i2 + t0 * 16 + ((((lg >> 1) << 3) ^ SWZ8(t0)) + (lg & 1) * 4);
    int ra3 = t0 + 9 * (lg >> 1);
    const unsigned short* pa3 = i2 + ra3 * 16 + (((lg & 1) << 3) ^ SWZ8(ra3));
    const unsigned short* pb3 = i2 + (ra3 + 18) * 16 + (((lg & 1) << 3) ^ SWZ8(ra3 + 18));
    unsigned short* ps3 = s3 + lm * 520 + wv * 16 + 4 * lg;
    const unsigned short* pd  = s3 + lm * 520 + wv * 128 + lg * 8;
    const unsigned short* xrow = x3b + (size_t)(b16 + lm) * T3P;

    f32x4 dacc;
#pragma unroll
    for (int r = 0; r < 4; ++r) dacc[r] = 0.f;
    float nstc = 0.f;

    // ---- preload chunk 0 sinb into regs ----
    int c0 = (G * 4) * 512;
    int n_in = min(512, T3_ - c0) + 26;
    float r0 = seq[c0 + tid];
    float r1 = seq[c0 + tid + 256];
    float r2 = (tid + 512 < n_in) ? seq[c0 + tid + 512] : 0.f;

    for (int cc = 0; cc < 4; ++cc) {
        c0 = (G * 4 + cc) * 512;
        int Lv = min(512, T3_ - c0);
        int n1 = Lv + 24;
        n_in = Lv + 26;

        // ---- write staged regs -> sinb ----
        sinb[tid] = r0;
        sinb[tid + 256] = r1;
        if (tid + 512 < n_in) sinb[tid + 512] = r2;
        __syncthreads();

        // ---- conv1 (MFMA, Hankel B from sinb; broadcast reads, zero-A masks lg>0) ----
        // also: zero i1 tail rows, issue bq (dot B-frag) loads, issue next-chunk sinb loads
        uint4 bq[4];
#pragma unroll
        for (int kk = 0; kk < 4; ++kk) {
            int tg = c0 + wv * 128 + kk * 32 + lg * 8;
            int tc = (tg > 8160) ? 0 : tg;
            bq[kk] = *(const uint4*)(xrow + tc);
        }
        if (cc < 3) {
            int c0n = c0 + 512;
            int n_in_n = min(512, T3_ - c0n) + 26;
            r0 = seq[c0n + tid];
            r1 = seq[c0n + tid + 256];
            r2 = (tid + 512 < n_in_n) ? seq[c0n + tid + 512] : 0.f;
        }
        for (int z = tid; z < (560 - n1) * 8; z += 256)
            ((unsigned int*)(i1 + n1 * 16))[z] = 0;
#pragma unroll
        for (int k = 0; k < 9; ++k) {
            if (k == 8 && wv >= 2) break;
            float s0 = p1[64 * k], s1 = p1[64 * k + 1], s2 = p1[64 * k + 2];
            uint4 bfv = { pk2(s0, s1), pk2(s2, 0.f), 0u, 0u };
            f32x4 acc = __builtin_amdgcn_mfma_f32_16x16x32_bf16(W1f, as_bf(bfv), c1v, 0, 0, 0);
            if (t0 + 64 * k < n1) {
                uint2 pq = { pk2(fmaxf(acc[0], 0.f), fmaxf(acc[1], 0.f)),
                             pk2(fmaxf(acc[2], 0.f), fmaxf(acc[3], 0.f)) };
                *(uint2*)(pw1 + 1024 * k) = pq;
            }
        }
        __syncthreads();

        // ---- conv2 d=3 ----
#pragma unroll
        for (int k = 0; k < 9; ++k) {
            if (k == 8 && wv >= 2) break;
            bf16x8 Ba = *(const bf16x8*)(pa2 + 1024 * k);
            bf16x8 Bb = *(const bf16x8*)(pb2 + 1024 * k);
            f32x4 acc = c2v;
            acc = __builtin_amdgcn_mfma_f32_16x16x32_bf16(W2a, Ba, acc, 0, 0, 0);
            acc = __builtin_amdgcn_mfma_f32_16x16x32_bf16(W2b, Bb, acc, 0, 0, 0);
            uint2 pq = { pk2(fmaxf(acc[0], 0.f), fmaxf(acc[1], 0.f)),
                         pk2(fmaxf(acc[2], 0.f), fmaxf(acc[3], 0.f)) };
            *(uint2*)(pw2 + 1024 * k) = pq;
        }
        __syncthreads();

        // ---- conv3 d=9 transposed -> s3 (b64 contiguous-t writes) + norm ----
#pragma unroll
        for (int k = 0; k < 8; ++k) {
            bf16x8 Aa = *(const bf16x8*)(pa3 + 1024 * k);
            bf16x8 Ab = *(const bf16x8*)(pb3 + 1024 * k);
            f32x4 acc = c3v;
            acc = __builtin_amdgcn_mfma_f32_16x16x32_bf16(Aa, W3a, acc, 0, 0, 0);
            acc = __builtin_amdgcn_mfma_f32_16x16x32_bf16(Ab, W3b, acc, 0, 0, 0);
            int u4 = wv * 16 + 4 * lg + 64 * k;
            float v[4];
#pragma unroll
            for (int r = 0; r < 4; ++r) {
                float x = ((u4 + r) < Lv) ? fmaxf(acc[r], 0.f) : 0.f;
                v[r] = x;
                nstc += x * x;
            }
            uint2 pq = { pk2(v[0], v[1]), pk2(v[2], v[3]) };
            *(uint2*)(ps3 + 64 * k) = pq;
        }
        __syncthreads();

        // ---- dot (MFMA): dacc += s3 . x3^T, B prefetched ----
#pragma unroll
        for (int kk = 0; kk < 4; ++kk) {
            bf16x8 Af = *(const bf16x8*)(pd + 32 * kk);
            dacc = __builtin_amdgcn_mfma_f32_16x16x32_bf16(Af, as_bf(bq[kk]), dacc, 0, 0, 0);
        }
        __syncthreads();   // s3(=i1) free before next conv1 writes; sinb free before next write
    }

    // nst: lane holds channel lm partial; reduce over lg (lanes +16, +32)
    nstc += __shfl_xor(nstc, 16);
    nstc += __shfl_xor(nstc, 32);
    int ob = (bs * 4 + G) * 4 + wv;
    *(f32x4*)(dotp + (size_t)ob * 256 + lane * 4) = dacc;
    if (lg == 0) nstp[(size_t)ob * 16 + lm] = nstc;
}

// =========== K5: reduce partials, cosine, linear head ===========
__global__ __launch_bounds__(256) void k_head(const float* __restrict__ dotp,
                                              const float* __restrict__ nstp,
                                              const float* __restrict__ nxp,
                                              const float* __restrict__ wlin,
                                              const float* __restrict__ blin,
                                              float* __restrict__ out) {
    int bs = blockIdx.x, tid = threadIdx.x;
    int b = bs >> 3;
    __shared__ float nxv[16];
    if (tid < 16) {
        float s = 0.f;
#pragma unroll
        for (int ch = 0; ch < 32; ++ch) s += nxp[((size_t)b * 16 + tid) * 32 + ch];
        nxv[tid] = fmaxf(sqrtf(s), EPS_);
    }
    __syncthreads();
    int i = 4 * (tid >> 6) + (tid & 3);
    int j = (tid >> 2) & 15;
    float dot = 0.f, ss = 0.f;
#pragma unroll
    for (int gw = 0; gw < 16; ++gw) {
        dot += dotp[(size_t)(bs * 16 + gw) * 256 + tid];
        ss  += nstp[(size_t)(bs * 16 + gw) * 16 + i];
    }
    float nstv = fmaxf(sqrtf(ss), EPS_);
    float val = dot / (nstv * nxv[j]) * wlin[i * 16 + j];
#pragma unroll
    for (int m = 32; m > 0; m >>= 1) val += __shfl_down(val, m, 64);
    __shared__ float rd[4];
    if ((tid & 63) == 0) rd[tid >> 6] = val;
    __syncthreads();
    if (tid == 0) out[bs] = rd[0] + rd[1] + rd[2] + rd[3] + blin[0];
}

extern "C" void kernel_launch(void* const* d_in, const int* in_sizes, int n_in,
                              void* d_out, int out_size, void* d_ws, size_t ws_size,
                              hipStream_t stream) {
    const float* eeg   = (const float*)d_in[0];
    const float* stim  = (const float*)d_in[1];
    const float* w_eeg = (const float*)d_in[2];
    const float* b_eeg = (const float*)d_in[3];
    const float* w_e1  = (const float*)d_in[4];
    const float* b_e1  = (const float*)d_in[5];
    const float* w_e2  = (const float*)d_in[6];
    const float* b_e2  = (const float*)d_in[7];
    const float* w_e3  = (const float*)d_in[8];
    const float* b_e3  = (const float*)d_in[9];
    const float* w_s1  = (const float*)d_in[10];
    const float* b_s1  = (const float*)d_in[11];
    const float* w_s2  = (const float*)d_in[12];
    const float* b_s2  = (const float*)d_in[13];
    const float* w_s3  = (const float*)d_in[14];
    const float* b_s3  = (const float*)d_in[15];
    const float* w_lin = (const float*)d_in[16];
    const float* b_lin = (const float*)d_in[17];

    unsigned char* ws = (unsigned char*)d_ws;
    unsigned short* x3b  = (unsigned short*)ws;                 // 16,728,064 B
    float*          nxp  = (float*)(ws + 16728064);             // 131,072 B
    float*          dotp = (float*)(ws + 16859136);             // 8,388,608 B
    float*          nstp = (float*)(ws + 25247744);             // 524,288 B
    unsigned short* x0b  = (unsigned short*)(ws + 25772032);    // 8,388,608 B
    unsigned short* wfE  = (unsigned short*)(ws + 34160640);    // 5,120 B
    unsigned short* wfS  = (unsigned short*)(ws + 34165760);    // 5,120 B
    float*          out  = (float*)d_out;

    k_pack<<<1, 256, 0, stream>>>(w_e1, w_e2, w_e3, w_s1, w_s2, w_s3, wfE, wfS);
    k_eeg1x1<<<(B_ * T_) / 256, 256, 0, stream>>>(eeg, w_eeg, b_eeg, x0b);
    k_estack<<<dim3(32, B_), 256, 0, stream>>>(x0b, b_e1, b_e2, b_e3, wfE, x3b, nxp);
    k_stim<<<dim3(B_ * S_, 4), 256, 0, stream>>>(stim, b_s1, b_s2, b_s3,
                                                 wfS, x3b, dotp, nstp);
    k_head<<<B_ * S_, 256, 0, stream>>>(dotp, nstp, nxp, w_lin, b_lin, out);
}

// Round 9
// 123.549 us; speedup vs baseline: 1.2314x; 1.0199x over previous
//
#include <hip/hip_runtime.h>
#include <hip/hip_bf16.h>
#include <math.h>

#define B_   64
#define S_   8
#define T_   8192
#define T3_  8166      // 8192 - 26
#define T3P  8168      // padded row stride
#define EPS_ 1e-8f
#define SWZ8(r) ((((r) >> 2) & 1) << 3)   // half-swizzle: XOR of the 16B-half by row bit 2

typedef __bf16 bf16x8 __attribute__((ext_vector_type(8)));
typedef float  f32x4  __attribute__((ext_vector_type(4)));

__device__ __forceinline__ unsigned short f2bf(float x) {
    __hip_bfloat16 h = __float2bfloat16(x);
    return *reinterpret_cast<unsigned short*>(&h);
}
__device__ __forceinline__ unsigned int pk2(float a, float b) {
    return (unsigned int)f2bf(a) | ((unsigned int)f2bf(b) << 16);
}
__device__ __forceinline__ bf16x8 as_bf(uint4 u) { return *reinterpret_cast<bf16x8*>(&u); }

// =========== K0: pack MFMA weight fragments to global (bf16) ===========
__global__ __launch_bounds__(256) void k_pack(
        const float* __restrict__ w_e1, const float* __restrict__ w_e2, const float* __restrict__ w_e3,
        const float* __restrict__ w_s1, const float* __restrict__ w_s2, const float* __restrict__ w_s3,
        unsigned short* __restrict__ wfE, unsigned short* __restrict__ wfS) {
    int tid = threadIdx.x;
    for (int idx = tid; idx < 2560; idx += 256) {
        int arr = idx >> 9, e = idx & 511;
        int m = e >> 5, k5 = e & 31;
        float v = 0.f;
        if (arr == 0)      { int tap = k5 >> 3, ci = k5 & 7; if (tap < 3) v = w_e1[(m * 8 + ci) * 3 + tap]; }
        else if (arr == 1) { int tap = k5 >> 4, ci = k5 & 15; v = w_e2[(m * 16 + ci) * 3 + tap]; }
        else if (arr == 2) { if (k5 < 16) v = w_e2[(m * 16 + k5) * 3 + 2]; }
        else if (arr == 3) { int tap = k5 >> 4, ci = k5 & 15; v = w_e3[(m * 16 + ci) * 3 + tap]; }
        else               { if (k5 < 16) v = w_e3[(m * 16 + k5) * 3 + 2]; }
        wfE[idx] = f2bf(v);
    }
    for (int idx = tid; idx < 2560; idx += 256) {
        int arr = idx >> 9, e = idx & 511;
        int m = e >> 5, k5 = e & 31;
        float v = 0.f;
        if (arr == 0)      { if (k5 < 3) v = w_s1[m * 3 + k5]; }
        else if (arr == 1) { int tap = k5 >> 4, ci = k5 & 15; v = w_s2[(m * 16 + ci) * 3 + tap]; }
        else if (arr == 2) { if (k5 < 16) v = w_s2[(m * 16 + k5) * 3 + 2]; }
        else if (arr == 3) { int tap = k5 >> 4, ci = k5 & 15; v = w_s3[(m * 16 + ci) * 3 + tap]; }
        else               { if (k5 < 16) v = w_s3[(m * 16 + k5) * 3 + 2]; }
        wfS[idx] = f2bf(v);
    }
}

// =========== KA: streaming 1x1 conv 64->8, [B,T,64] f32 -> [B,T,8] bf16 ===========
__global__ __launch_bounds__(256) void k_eeg1x1(const float* __restrict__ eeg,
                                                const float* __restrict__ w,
                                                const float* __restrict__ bias,
                                                unsigned short* __restrict__ x0b) {
    __shared__ float ws[512];
    __shared__ float bs[8];
    int tid = threadIdx.x;
    ws[tid]       = w[tid];
    ws[tid + 256] = w[tid + 256];
    if (tid < 8) bs[tid] = bias[tid];
    __syncthreads();

    int gt = blockIdx.x * 256 + tid;
    const float* ep = eeg + (size_t)gt * 64;

    float acc[8];
#pragma unroll
    for (int c = 0; c < 8; ++c) acc[c] = bs[c];
#pragma unroll
    for (int i = 0; i < 64; i += 4) {
        float4 v = *(const float4*)(ep + i);
#pragma unroll
        for (int c = 0; c < 8; ++c) {
            const float* wp = ws + c * 64 + i;
            acc[c] += v.x * wp[0] + v.y * wp[1] + v.z * wp[2] + v.w * wp[3];
        }
    }
    uint4 p = { pk2(acc[0], acc[1]), pk2(acc[2], acc[3]),
                pk2(acc[4], acc[5]), pk2(acc[6], acc[7]) };
    *(uint4*)(x0b + (size_t)gt * 8) = p;
}

// =========== KB: eeg dilated stack, unrolled const-offset MFMA, transposed conv3 ===========
// grid (32 chunks, 64 b), 256 threads, 24KB LDS
__global__ __launch_bounds__(256) void k_estack(const unsigned short* __restrict__ x0b,
        const float* __restrict__ b1, const float* __restrict__ b2, const float* __restrict__ b3,
        const unsigned short* __restrict__ wfE,
        unsigned short* __restrict__ x3b, float* __restrict__ nxp) {
    // LDS: x0T u16[304][8] @0 ; i1 u16[304][16] @4864 ; i2 u16[288][16] @14592 ; wred f32[64] @23808
    // st3 u16[16][264] @0 aliases x0T + i1 head (both dead by conv3)
    __shared__ __align__(16) unsigned char smem[24064];
    unsigned short* x0T = (unsigned short*)smem;
    unsigned short* i1  = (unsigned short*)(smem + 4864);
    unsigned short* i2  = (unsigned short*)(smem + 14592);
    float*          wred= (float*)(smem + 23808);
    unsigned short* st3 = (unsigned short*)smem;

    int tid = threadIdx.x;
    int chunk = blockIdx.x, b = blockIdx.y;
    int wv = tid >> 6, lane = tid & 63, lm = lane & 15, lg = lane >> 4;

    int c0 = chunk * 256;
    int Lv = min(256, T3_ - c0);
    int n_in = Lv + 26, n1 = Lv + 24;

    // ---- stage x0 rows [0,304): load valid, zero rest ----
    {
        const unsigned short* src = x0b + ((size_t)b * T_ + c0) * 8;
        uint4 z = {0, 0, 0, 0};
        for (int r = tid; r < 304; r += 256) {
            uint4 v = (r < n_in) ? *(const uint4*)(src + r * 8) : z;
            *(uint4*)(x0T + r * 8) = v;
        }
    }
    // ---- zero i1 rows [n1, 304) (conv1 writes are guarded at n1) ----
    for (int idx = tid; idx < (304 - n1) * 8; idx += 256)
        ((unsigned int*)(i1 + n1 * 16))[idx] = 0;
    __syncthreads();

    const bf16x8 W1f = *(const bf16x8*)(wfE +         lm * 32 + 8 * lg);
    const bf16x8 W2a = *(const bf16x8*)(wfE + 512  +  lm * 32 + 8 * lg);
    const bf16x8 W2b = *(const bf16x8*)(wfE + 1024 +  lm * 32 + 8 * lg);
    const bf16x8 W3a = *(const bf16x8*)(wfE + 1536 +  lm * 32 + 8 * lg);
    const bf16x8 W3b = *(const bf16x8*)(wfE + 2048 +  lm * 32 + 8 * lg);
    f32x4 c1v, c2v, c3v;
#pragma unroll
    for (int r = 0; r < 4; ++r) {
        c1v[r] = b1[4 * lg + r];
        c2v[r] = b2[4 * lg + r];
        c3v[r] = b3[lm];          // transposed conv3: C col = channel = lm
    }

    // ---- hoisted per-lane swizzled bases (SWZ8 invariant under +64-row steps) ----
    int t0 = wv * 16 + lm;
    const unsigned short* px0 = x0T + (t0 + lg) * 8;
    unsigned short* pw1 = i1 + t0 * 16 + ((((lg >> 1) << 3) ^ SWZ8(t0)) + (lg & 1) * 4);
    int ra2 = t0 + 3 * (lg >> 1);
    const unsigned short* pa2 = i1 + ra2 * 16 + (((lg & 1) << 3) ^ SWZ8(ra2));
    const unsigned short* pb2 = i1 + (ra2 + 6) * 16 + (((lg & 1) << 3) ^ SWZ8(ra2 + 6));
    unsigned short* pw2 = i2 + t0 * 16 + ((((lg >> 1) << 3) ^ SWZ8(t0)) + (lg & 1) * 4);
    int ra3 = t0 + 9 * (lg >> 1);
    const unsigned short* pa3 = i2 + ra3 * 16 + (((lg & 1) << 3) ^ SWZ8(ra3));
    const unsigned short* pb3 = i2 + (ra3 + 18) * 16 + (((lg & 1) << 3) ^ SWZ8(ra3 + 18));
    unsigned short* ps3 = st3 + lm * 264 + wv * 16 + 4 * lg;

    // ---- conv1 d=1 cin=8 (rows t0+64k, write-guard < n1) ----
#pragma unroll
    for (int k = 0; k < 5; ++k) {
        if (k == 4 && wv >= 2) break;
        bf16x8 Ba = *(const bf16x8*)(px0 + 512 * k);
        f32x4 acc = __builtin_amdgcn_mfma_f32_16x16x32_bf16(W1f, Ba, c1v, 0, 0, 0);
        if (t0 + 64 * k < n1) {
            uint2 pq = { pk2(fmaxf(acc[0], 0.f), fmaxf(acc[1], 0.f)),
                         pk2(fmaxf(acc[2], 0.f), fmaxf(acc[3], 0.f)) };
            *(uint2*)(pw1 + 1024 * k) = pq;
        }
    }
    __syncthreads();

    // ---- conv2 d=3 (rows 0..287 covered exactly by k<5 minus (wv>=2,k==4)) ----
#pragma unroll
    for (int k = 0; k < 5; ++k) {
        if (k == 4 && wv >= 2) break;
        bf16x8 Ba = *(const bf16x8*)(pa2 + 1024 * k);
        bf16x8 Bb = *(const bf16x8*)(pb2 + 1024 * k);
        f32x4 acc = c2v;
        acc = __builtin_amdgcn_mfma_f32_16x16x32_bf16(W2a, Ba, acc, 0, 0, 0);
        acc = __builtin_amdgcn_mfma_f32_16x16x32_bf16(W2b, Bb, acc, 0, 0, 0);
        uint2 pq = { pk2(fmaxf(acc[0], 0.f), fmaxf(acc[1], 0.f)),
                     pk2(fmaxf(acc[2], 0.f), fmaxf(acc[3], 0.f)) };
        *(uint2*)(pw2 + 1024 * k) = pq;
    }
    __syncthreads();

    // ---- conv3 d=9 transposed -> st3 [ch][264] (b64 contiguous-t writes) + norm ----
    float nstc = 0.f;
#pragma unroll
    for (int k = 0; k < 4; ++k) {
        bf16x8 Aa = *(const bf16x8*)(pa3 + 1024 * k);
        bf16x8 Ab = *(const bf16x8*)(pb3 + 1024 * k);
        f32x4 acc = c3v;
        acc = __builtin_amdgcn_mfma_f32_16x16x32_bf16(Aa, W3a, acc, 0, 0, 0);
        acc = __builtin_amdgcn_mfma_f32_16x16x32_bf16(Ab, W3b, acc, 0, 0, 0);
        int u4 = wv * 16 + 4 * lg + 64 * k;
        float v[4];
#pragma unroll
        for (int r = 0; r < 4; ++r) {
            float x = ((u4 + r) < Lv) ? fmaxf(acc[r], 0.f) : 0.f;
            v[r] = x;
            nstc += x * x;
        }
        uint2 pq = { pk2(v[0], v[1]), pk2(v[2], v[3]) };
        *(uint2*)(ps3 + 64 * k) = pq;
    }
    // nstc: lane holds channel lm partial; reduce over lg then waves
    nstc += __shfl_xor(nstc, 16);
    nstc += __shfl_xor(nstc, 32);
    if (lg == 0) wred[wv * 16 + lm] = nstc;
    __syncthreads();

    if (tid < 16) {
        float s = wred[tid] + wred[16 + tid] + wred[32 + tid] + wred[48 + tid];
        nxp[((size_t)b * 16 + tid) * 32 + chunk] = s;
    }
    // ---- coalesced st3 -> x3b ----
    {
        unsigned short* dst = x3b + (size_t)(b * 16) * T3P + c0;
        for (int idx = tid; idx < 16 * 32; idx += 256) {
            int co = idx >> 5, off = (idx & 31) * 8;
            if (off + 8 <= Lv)
                *(uint4*)(dst + (size_t)co * T3P + off) = *(const uint4*)(st3 + co * 264 + off);
            else
                for (int k = off; k < Lv; ++k) dst[(size_t)co * T3P + k] = st3[co * 264 + k];
        }
        if (chunk == 31 && tid < 16)
            *(unsigned int*)(x3b + (size_t)(b * 16 + tid) * T3P + T3_) = 0;
    }
}

// =========== K4: stim stack, unrolled const-offset MFMA, chunk=512, prefetched ===========
// grid (512 bs, 4 G); in-kernel cross-wave reduction of dot/norm partials.
__global__ __launch_bounds__(256, 4) void k_stim(const float* __restrict__ stim,
                                              const float* __restrict__ b1,
                                              const float* __restrict__ b2,
                                              const float* __restrict__ b3,
                                              const unsigned short* __restrict__ wfS,
                                              const unsigned short* __restrict__ x3b,
                                              float* __restrict__ dotp, float* __restrict__ nstp) {
    // LDS: sinb f32[548] @0 (2192) ; i1 u16[560][16] @2192 (17920) ; i2 u16[544][16] @20112 (17408)
    // s3 u16[16][520] aliases i1 (dead after conv2); red f32[816] @0 aliases sinb+i1 head (end only)
    __shared__ __align__(16) unsigned char smem[37520];
    float*          sinb = (float*)smem;
    unsigned short* i1   = (unsigned short*)(smem + 2192);
    unsigned short* i2   = (unsigned short*)(smem + 20112);
    unsigned short* s3   = i1;

    int tid  = threadIdx.x;
    int bs   = blockIdx.x;
    int G    = blockIdx.y;
    int wv   = tid >> 6;
    int lane = tid & 63;
    int lm   = lane & 15;
    int lg   = lane >> 4;

    const bf16x8 W1f = *(const bf16x8*)(wfS +         lm * 32 + 8 * lg);
    const bf16x8 W2a = *(const bf16x8*)(wfS + 512  +  lm * 32 + 8 * lg);
    const bf16x8 W2b = *(const bf16x8*)(wfS + 1024 +  lm * 32 + 8 * lg);
    const bf16x8 W3a = *(const bf16x8*)(wfS + 1536 +  lm * 32 + 8 * lg);
    const bf16x8 W3b = *(const bf16x8*)(wfS + 2048 +  lm * 32 + 8 * lg);
    f32x4 c1v, c2v, c3v;
#pragma unroll
    for (int r = 0; r < 4; ++r) {
        c1v[r] = b1[4 * lg + r];
        c2v[r] = b2[4 * lg + r];
        c3v[r] = b3[lm];          // transposed conv3: C col = channel = lm
    }

    const float* seq = stim + (size_t)bs * T_;
    int b16 = (bs >> 3) * 16;

    // ---- hoisted per-lane swizzled bases (SWZ8 invariant under +64-row steps) ----
    int t0   = wv * 16 + lm;
    const float*    p1  = sinb + t0;
    unsigned short* pw1 = i1 + t0 * 16 + ((((lg >> 1) << 3) ^ SWZ8(t0)) + (lg & 1) * 4);
    int ra2 = t0 + 3 * (lg >> 1);
    const unsigned short* pa2 = i1 + ra2 * 16 + (((lg & 1) << 3) ^ SWZ8(ra2));
    const unsigned short* pb2 = i1 + (ra2 + 6) * 16 + (((lg & 1) << 3) ^ SWZ8(ra2 + 6));
    unsigned short* pw2 = i2 + t0 * 16 + ((((lg >> 1) << 3) ^ SWZ8(t0)) + (lg & 1) * 4);
    int ra3 = t0 + 9 * (lg >> 1);
    const unsigned short* pa3 = i2 + ra3 * 16 + (((lg & 1) << 3) ^ SWZ8(ra3));
    const unsigned short* pb3 = i2 + (ra3 + 18) * 16 + (((lg & 1) << 3) ^ SWZ8(ra3 + 18));
    unsigned short* ps3 = s3 + lm * 520 + wv * 16 + 4 * lg;
    const unsigned short* pd  = s3 + lm * 520 + wv * 128 + lg * 8;
    const unsigned short* xrow = x3b + (size_t)(b16 + lm) * T3P;

    f32x4 dacc;
#pragma unroll
    for (int r = 0; r < 4; ++r) dacc[r] = 0.f;
    float nstc = 0.f;

    // ---- preload chunk 0 sinb into regs ----
    int c0 = (G * 4) * 512;
    int n_in = min(512, T3_ - c0) + 26;
    float r0 = seq[c0 + tid];
    float r1 = seq[c0 + tid + 256];
    float r2 = (tid + 512 < n_in) ? seq[c0 + tid + 512] : 0.f;

    for (int cc = 0; cc < 4; ++cc) {
        c0 = (G * 4 + cc) * 512;
        int Lv = min(512, T3_ - c0);
        int n1 = Lv + 24;
        n_in = Lv + 26;

        sinb[tid] = r0;
        sinb[tid + 256] = r1;
        if (tid + 512 < n_in) sinb[tid + 512] = r2;
        __syncthreads();

        // ---- conv1 (MFMA, Hankel B from sinb); bq + next-sinb prefetch; zero i1 tail ----
        uint4 bq[4];
#pragma unroll
        for (int kk = 0; kk < 4; ++kk) {
            int tg = c0 + wv * 128 + kk * 32 + lg * 8;
            int tc = (tg > 8160) ? 0 : tg;
            bq[kk] = *(const uint4*)(xrow + tc);
        }
        if (cc < 3) {
            int c0n = c0 + 512;
            int n_in_n = min(512, T3_ - c0n) + 26;
            r0 = seq[c0n + tid];
            r1 = seq[c0n + tid + 256];
            r2 = (tid + 512 < n_in_n) ? seq[c0n + tid + 512] : 0.f;
        }
        for (int z = tid; z < (560 - n1) * 8; z += 256)
            ((unsigned int*)(i1 + n1 * 16))[z] = 0;
#pragma unroll
        for (int k = 0; k < 9; ++k) {
            if (k == 8 && wv >= 2) break;
            float s0 = p1[64 * k], s1 = p1[64 * k + 1], s2 = p1[64 * k + 2];
            uint4 bfv = { pk2(s0, s1), pk2(s2, 0.f), 0u, 0u };
            f32x4 acc = __builtin_amdgcn_mfma_f32_16x16x32_bf16(W1f, as_bf(bfv), c1v, 0, 0, 0);
            if (t0 + 64 * k < n1) {
                uint2 pq = { pk2(fmaxf(acc[0], 0.f), fmaxf(acc[1], 0.f)),
                             pk2(fmaxf(acc[2], 0.f), fmaxf(acc[3], 0.f)) };
                *(uint2*)(pw1 + 1024 * k) = pq;
            }
        }
        __syncthreads();

        // ---- conv2 d=3 ----
#pragma unroll
        for (int k = 0; k < 9; ++k) {
            if (k == 8 && wv >= 2) break;
            bf16x8 Ba = *(const bf16x8*)(pa2 + 1024 * k);
            bf16x8 Bb = *(const bf16x8*)(pb2 + 1024 * k);
            f32x4 acc = c2v;
            acc = __builtin_amdgcn_mfma_f32_16x16x32_bf16(W2a, Ba, acc, 0, 0, 0);
            acc = __builtin_amdgcn_mfma_f32_16x16x32_bf16(W2b, Bb, acc, 0, 0, 0);
            uint2 pq = { pk2(fmaxf(acc[0], 0.f), fmaxf(acc[1], 0.f)),
                         pk2(fmaxf(acc[2], 0.f), fmaxf(acc[3], 0.f)) };
            *(uint2*)(pw2 + 1024 * k) = pq;
        }
        __syncthreads();

        // ---- conv3 d=9 transposed -> s3 + norm ----
#pragma unroll
        for (int k = 0; k < 8; ++k) {
            bf16x8 Aa = *(const bf16x8*)(pa3 + 1024 * k);
            bf16x8 Ab = *(const bf16x8*)(pb3 + 1024 * k);
            f32x4 acc = c3v;
            acc = __builtin_amdgcn_mfma_f32_16x16x32_bf16(Aa, W3a, acc, 0, 0, 0);
            acc = __builtin_amdgcn_mfma_f32_16x16x32_bf16(Ab, W3b, acc, 0, 0, 0);
            int u4 = wv * 16 + 4 * lg + 64 * k;
            float v[4];
#pragma unroll
            for (int r = 0; r < 4; ++r) {
                float x = ((u4 + r) < Lv) ? fmaxf(acc[r], 0.f) : 0.f;
                v[r] = x;
                nstc += x * x;
            }
            uint2 pq = { pk2(v[0], v[1]), pk2(v[2], v[3]) };
            *(uint2*)(ps3 + 64 * k) = pq;
        }
        __syncthreads();

        // ---- dot (MFMA): dacc += s3 . x3^T, B prefetched ----
#pragma unroll
        for (int kk = 0; kk < 4; ++kk) {
            bf16x8 Af = *(const bf16x8*)(pd + 32 * kk);
            dacc = __builtin_amdgcn_mfma_f32_16x16x32_bf16(Af, as_bf(bq[kk]), dacc, 0, 0, 0);
        }
        __syncthreads();   // s3(=i1) free before next conv1 writes; sinb free before next write
    }

    // ---- cross-wave reduction in LDS (sinb/i1 dead): dotp shrinks 4x ----
    nstc += __shfl_xor(nstc, 16);
    nstc += __shfl_xor(nstc, 32);
    float* red  = (float*)smem;            // 768 f32 = 3072B
    float* redn = (float*)(smem + 3072);   // 48 f32
    if (wv > 0) {
        *(f32x4*)(red + ((wv - 1) * 64 + lane) * 4) = dacc;
        if (lg == 0) redn[(wv - 1) * 16 + lm] = nstc;
    }
    __syncthreads();
    if (wv == 0) {
#pragma unroll
        for (int w = 0; w < 3; ++w) {
            f32x4 o = *(const f32x4*)(red + (w * 64 + lane) * 4);
#pragma unroll
            for (int r = 0; r < 4; ++r) dacc[r] += o[r];
        }
        int ob = bs * 4 + G;
        *(f32x4*)(dotp + (size_t)ob * 256 + lane * 4) = dacc;
        if (lg == 0)
            nstp[(size_t)ob * 16 + lm] = nstc + redn[lm] + redn[16 + lm] + redn[32 + lm];
    }
}

// =========== K5: reduce partials, cosine, linear head ===========
__global__ __launch_bounds__(256) void k_head(const float* __restrict__ dotp,
                                              const float* __restrict__ nstp,
                                              const float* __restrict__ nxp,
                                              const float* __restrict__ wlin,
                                              const float* __restrict__ blin,
                                              float* __restrict__ out) {
    int bs = blockIdx.x, tid = threadIdx.x;
    int b = bs >> 3;
    __shared__ float nxv[16];
    if (tid < 16) {
        float s = 0.f;
#pragma unroll
        for (int ch = 0; ch < 32; ++ch) s += nxp[((size_t)b * 16 + tid) * 32 + ch];
        nxv[tid] = fmaxf(sqrtf(s), EPS_);
    }
    __syncthreads();
    int i = 4 * (tid >> 6) + (tid & 3);
    int j = (tid >> 2) & 15;
    float dot = 0.f, ss = 0.f;
#pragma unroll
    for (int gw = 0; gw < 4; ++gw) {
        dot += dotp[(size_t)(bs * 4 + gw) * 256 + tid];
        ss  += nstp[(size_t)(bs * 4 + gw) * 16 + i];
    }
    float nstv = fmaxf(sqrtf(ss), EPS_);
    float val = dot / (nstv * nxv[j]) * wlin[i * 16 + j];
#pragma unroll
    for (int m = 32; m > 0; m >>= 1) val += __shfl_down(val, m, 64);
    __shared__ float rd[4];
    if ((tid & 63) == 0) rd[tid >> 6] = val;
    __syncthreads();
    if (tid == 0) out[bs] = rd[0] + rd[1] + rd[2] + rd[3] + blin[0];
}

extern "C" void kernel_launch(void* const* d_in, const int* in_sizes, int n_in,
                              void* d_out, int out_size, void* d_ws, size_t ws_size,
                              hipStream_t stream) {
    const float* eeg   = (const float*)d_in[0];
    const float* stim  = (const float*)d_in[1];
    const float* w_eeg = (const float*)d_in[2];
    const float* b_eeg = (const float*)d_in[3];
    const float* w_e1  = (const float*)d_in[4];
    const float* b_e1  = (const float*)d_in[5];
    const float* w_e2  = (const float*)d_in[6];
    const float* b_e2  = (const float*)d_in[7];
    const float* w_e3  = (const float*)d_in[8];
    const float* b_e3  = (const float*)d_in[9];
    const float* w_s1  = (const float*)d_in[10];
    const float* b_s1  = (const float*)d_in[11];
    const float* w_s2  = (const float*)d_in[12];
    const float* b_s2  = (const float*)d_in[13];
    const float* w_s3  = (const float*)d_in[14];
    const float* b_s3  = (const float*)d_in[15];
    const float* w_lin = (const float*)d_in[16];
    const float* b_lin = (const float*)d_in[17];

    unsigned char* ws = (unsigned char*)d_ws;
    unsigned short* x3b  = (unsigned short*)ws;                 // 16,728,064 B
    float*          nxp  = (float*)(ws + 16728064);             // 131,072 B
    float*          dotp = (float*)(ws + 16859136);             // 2,097,152 B (512*4*256 f32)
    float*          nstp = (float*)(ws + 25247744);             // 131,072 B (512*4*16 f32)
    unsigned short* x0b  = (unsigned short*)(ws + 25772032);    // 8,388,608 B
    unsigned short* wfE  = (unsigned short*)(ws + 34160640);    // 5,120 B
    unsigned short* wfS  = (unsigned short*)(ws + 34165760);    // 5,120 B
    float*          out  = (float*)d_out;

    k_pack<<<1, 256, 0, stream>>>(w_e1, w_e2, w_e3, w_s1, w_s2, w_s3, wfE, wfS);
    k_eeg1x1<<<(B_ * T_) / 256, 256, 0, stream>>>(eeg, w_eeg, b_eeg, x0b);
    k_estack<<<dim3(32, B_), 256, 0, stream>>>(x0b, b_e1, b_e2, b_e3, wfE, x3b, nxp);
    k_stim<<<dim3(B_ * S_, 4), 256, 0, stream>>>(stim, b_s1, b_s2, b_s3,
                                                 wfS, x3b, dotp, nstp);
    k_head<<<B_ * S_, 256, 0, stream>>>(dotp, nstp, nxp, w_lin, b_lin, out);
}

// Round 10
// 113.954 us; speedup vs baseline: 1.3351x; 1.0842x over previous
//
#include <hip/hip_runtime.h>
#include <hip/hip_bf16.h>
#include <math.h>

#define B_   64
#define S_   8
#define T_   8192
#define T3_  8166      // 8192 - 26
#define T3P  8168      // padded row stride
#define EPS_ 1e-8f
#define SWZ8(r) ((((r) >> 2) & 1) << 3)   // half-swizzle: XOR of the 16B-half by row bit 2

typedef __bf16 bf16x8 __attribute__((ext_vector_type(8)));
typedef float  f32x4  __attribute__((ext_vector_type(4)));

__device__ __forceinline__ unsigned short f2bf(float x) {
    __hip_bfloat16 h = __float2bfloat16(x);
    return *reinterpret_cast<unsigned short*>(&h);
}
__device__ __forceinline__ unsigned int pk2(float a, float b) {
    return (unsigned int)f2bf(a) | ((unsigned int)f2bf(b) << 16);
}
__device__ __forceinline__ bf16x8 as_bf(uint4 u) { return *reinterpret_cast<bf16x8*>(&u); }

// =========== KA: streaming 1x1 conv 64->8 + (block 0) weight-fragment pack ===========
__global__ __launch_bounds__(256) void k_eeg1x1(const float* __restrict__ eeg,
                                                const float* __restrict__ w,
                                                const float* __restrict__ bias,
                                                unsigned short* __restrict__ x0b,
        const float* __restrict__ w_e1, const float* __restrict__ w_e2, const float* __restrict__ w_e3,
        const float* __restrict__ w_s2, const float* __restrict__ w_s3,
        unsigned short* __restrict__ wfE, unsigned short* __restrict__ wfS) {
    __shared__ float ws[512];
    __shared__ float bs[8];
    int tid = threadIdx.x;

    if (blockIdx.x == 0) {   // ---- pack MFMA weight fragments (bf16) ----
        for (int idx = tid; idx < 2560; idx += 256) {
            int arr = idx >> 9, e = idx & 511;
            int m = e >> 5, k5 = e & 31;
            float v = 0.f;
            if (arr == 0)      { int tap = k5 >> 3, ci = k5 & 7; if (tap < 3) v = w_e1[(m * 8 + ci) * 3 + tap]; }
            else if (arr == 1) { int tap = k5 >> 4, ci = k5 & 15; v = w_e2[(m * 16 + ci) * 3 + tap]; }
            else if (arr == 2) { if (k5 < 16) v = w_e2[(m * 16 + k5) * 3 + 2]; }
            else if (arr == 3) { int tap = k5 >> 4, ci = k5 & 15; v = w_e3[(m * 16 + ci) * 3 + tap]; }
            else               { if (k5 < 16) v = w_e3[(m * 16 + k5) * 3 + 2]; }
            wfE[idx] = f2bf(v);
        }
        for (int idx = tid; idx < 2048; idx += 256) {
            int arr = idx >> 9, e = idx & 511;
            int m = e >> 5, k5 = e & 31;
            int ci = k5 & 15, tap = k5 >> 4;
            float v;
            if (arr == 0)      v = w_s2[(m * 16 + ci) * 3 + tap];
            else if (arr == 1) v = (k5 < 16) ? w_s2[(m * 16 + k5) * 3 + 2] : 0.f;
            else if (arr == 2) v = w_s3[(m * 16 + ci) * 3 + tap];
            else               v = (k5 < 16) ? w_s3[(m * 16 + k5) * 3 + 2] : 0.f;
            wfS[idx] = f2bf(v);
        }
    }

    ws[tid]       = w[tid];
    ws[tid + 256] = w[tid + 256];
    if (tid < 8) bs[tid] = bias[tid];
    __syncthreads();

    int gt = blockIdx.x * 256 + tid;
    const float* ep = eeg + (size_t)gt * 64;

    float acc[8];
#pragma unroll
    for (int c = 0; c < 8; ++c) acc[c] = bs[c];
#pragma unroll
    for (int i = 0; i < 64; i += 4) {
        float4 v = *(const float4*)(ep + i);
#pragma unroll
        for (int c = 0; c < 8; ++c) {
            const float* wp = ws + c * 64 + i;
            acc[c] += v.x * wp[0] + v.y * wp[1] + v.z * wp[2] + v.w * wp[3];
        }
    }
    uint4 p = { pk2(acc[0], acc[1]), pk2(acc[2], acc[3]),
                pk2(acc[4], acc[5]), pk2(acc[6], acc[7]) };
    *(uint4*)(x0b + (size_t)gt * 8) = p;
}

// =========== KB: eeg dilated stack, unrolled const-offset MFMA (R9-verified) ===========
__global__ __launch_bounds__(256) void k_estack(const unsigned short* __restrict__ x0b,
        const float* __restrict__ b1, const float* __restrict__ b2, const float* __restrict__ b3,
        const unsigned short* __restrict__ wfE,
        unsigned short* __restrict__ x3b, float* __restrict__ nxp) {
    __shared__ __align__(16) unsigned char smem[24064];
    unsigned short* x0T = (unsigned short*)smem;
    unsigned short* i1  = (unsigned short*)(smem + 4864);
    unsigned short* i2  = (unsigned short*)(smem + 14592);
    float*          wred= (float*)(smem + 23808);
    unsigned short* st3 = (unsigned short*)smem;

    int tid = threadIdx.x;
    int chunk = blockIdx.x, b = blockIdx.y;
    int wv = tid >> 6, lane = tid & 63, lm = lane & 15, lg = lane >> 4;

    int c0 = chunk * 256;
    int Lv = min(256, T3_ - c0);
    int n_in = Lv + 26, n1 = Lv + 24;

    {
        const unsigned short* src = x0b + ((size_t)b * T_ + c0) * 8;
        uint4 z = {0, 0, 0, 0};
        for (int r = tid; r < 304; r += 256) {
            uint4 v = (r < n_in) ? *(const uint4*)(src + r * 8) : z;
            *(uint4*)(x0T + r * 8) = v;
        }
    }
    for (int idx = tid; idx < (304 - n1) * 8; idx += 256)
        ((unsigned int*)(i1 + n1 * 16))[idx] = 0;
    __syncthreads();

    const bf16x8 W1f = *(const bf16x8*)(wfE +         lm * 32 + 8 * lg);
    const bf16x8 W2a = *(const bf16x8*)(wfE + 512  +  lm * 32 + 8 * lg);
    const bf16x8 W2b = *(const bf16x8*)(wfE + 1024 +  lm * 32 + 8 * lg);
    const bf16x8 W3a = *(const bf16x8*)(wfE + 1536 +  lm * 32 + 8 * lg);
    const bf16x8 W3b = *(const bf16x8*)(wfE + 2048 +  lm * 32 + 8 * lg);
    f32x4 c1v, c2v, c3v;
#pragma unroll
    for (int r = 0; r < 4; ++r) {
        c1v[r] = b1[4 * lg + r];
        c2v[r] = b2[4 * lg + r];
        c3v[r] = b3[lm];
    }

    int t0 = wv * 16 + lm;
    const unsigned short* px0 = x0T + (t0 + lg) * 8;
    unsigned short* pw1 = i1 + t0 * 16 + ((((lg >> 1) << 3) ^ SWZ8(t0)) + (lg & 1) * 4);
    int ra2 = t0 + 3 * (lg >> 1);
    const unsigned short* pa2 = i1 + ra2 * 16 + (((lg & 1) << 3) ^ SWZ8(ra2));
    const unsigned short* pb2 = i1 + (ra2 + 6) * 16 + (((lg & 1) << 3) ^ SWZ8(ra2 + 6));
    unsigned short* pw2 = i2 + t0 * 16 + ((((lg >> 1) << 3) ^ SWZ8(t0)) + (lg & 1) * 4);
    int ra3 = t0 + 9 * (lg >> 1);
    const unsigned short* pa3 = i2 + ra3 * 16 + (((lg & 1) << 3) ^ SWZ8(ra3));
    const unsigned short* pb3 = i2 + (ra3 + 18) * 16 + (((lg & 1) << 3) ^ SWZ8(ra3 + 18));
    unsigned short* ps3 = st3 + lm * 264 + wv * 16 + 4 * lg;

#pragma unroll
    for (int k = 0; k < 5; ++k) {
        if (k == 4 && wv >= 2) break;
        bf16x8 Ba = *(const bf16x8*)(px0 + 512 * k);
        f32x4 acc = __builtin_amdgcn_mfma_f32_16x16x32_bf16(W1f, Ba, c1v, 0, 0, 0);
        if (t0 + 64 * k < n1) {
            uint2 pq = { pk2(fmaxf(acc[0], 0.f), fmaxf(acc[1], 0.f)),
                         pk2(fmaxf(acc[2], 0.f), fmaxf(acc[3], 0.f)) };
            *(uint2*)(pw1 + 1024 * k) = pq;
        }
    }
    __syncthreads();

#pragma unroll
    for (int k = 0; k < 5; ++k) {
        if (k == 4 && wv >= 2) break;
        bf16x8 Ba = *(const bf16x8*)(pa2 + 1024 * k);
        bf16x8 Bb = *(const bf16x8*)(pb2 + 1024 * k);
        f32x4 acc = c2v;
        acc = __builtin_amdgcn_mfma_f32_16x16x32_bf16(W2a, Ba, acc, 0, 0, 0);
        acc = __builtin_amdgcn_mfma_f32_16x16x32_bf16(W2b, Bb, acc, 0, 0, 0);
        uint2 pq = { pk2(fmaxf(acc[0], 0.f), fmaxf(acc[1], 0.f)),
                     pk2(fmaxf(acc[2], 0.f), fmaxf(acc[3], 0.f)) };
        *(uint2*)(pw2 + 1024 * k) = pq;
    }
    __syncthreads();

    float nstc = 0.f;
#pragma unroll
    for (int k = 0; k < 4; ++k) {
        bf16x8 Aa = *(const bf16x8*)(pa3 + 1024 * k);
        bf16x8 Ab = *(const bf16x8*)(pb3 + 1024 * k);
        f32x4 acc = c3v;
        acc = __builtin_amdgcn_mfma_f32_16x16x32_bf16(Aa, W3a, acc, 0, 0, 0);
        acc = __builtin_amdgcn_mfma_f32_16x16x32_bf16(Ab, W3b, acc, 0, 0, 0);
        int u4 = wv * 16 + 4 * lg + 64 * k;
        float v[4];
#pragma unroll
        for (int r = 0; r < 4; ++r) {
            float x = ((u4 + r) < Lv) ? fmaxf(acc[r], 0.f) : 0.f;
            v[r] = x;
            nstc += x * x;
        }
        uint2 pq = { pk2(v[0], v[1]), pk2(v[2], v[3]) };
        *(uint2*)(ps3 + 64 * k) = pq;
    }
    nstc += __shfl_xor(nstc, 16);
    nstc += __shfl_xor(nstc, 32);
    if (lg == 0) wred[wv * 16 + lm] = nstc;
    __syncthreads();

    if (tid < 16) {
        float s = wred[tid] + wred[16 + tid] + wred[32 + tid] + wred[48 + tid];
        nxp[((size_t)b * 16 + tid) * 32 + chunk] = s;
    }
    {
        unsigned short* dst = x3b + (size_t)(b * 16) * T3P + c0;
        for (int idx = tid; idx < 16 * 32; idx += 256) {
            int co = idx >> 5, off = (idx & 31) * 8;
            if (off + 8 <= Lv)
                *(uint4*)(dst + (size_t)co * T3P + off) = *(const uint4*)(st3 + co * 264 + off);
            else
                for (int k = off; k < Lv; ++k) dst[(size_t)co * T3P + k] = st3[co * 264 + k];
        }
        if (chunk == 31 && tid < 16)
            *(unsigned int*)(x3b + (size_t)(b * 16 + tid) * T3P + T3_) = 0;
    }
}

// =========== K4: stim stack — scalar conv1 (fp32), MFMA conv2/3, merged dot phase ===========
// grid (512 bs, 4 G); 4 barriers/chunk; in-kernel cross-wave partial reduction.
__global__ __launch_bounds__(256, 4) void k_stim(const float* __restrict__ stim,
                                              const float* __restrict__ w1,
                                              const float* __restrict__ b1,
                                              const float* __restrict__ b2,
                                              const float* __restrict__ b3,
                                              const unsigned short* __restrict__ wfS,
                                              const unsigned short* __restrict__ x3b,
                                              float* __restrict__ dotp, float* __restrict__ nstp) {
    // LDS: sinb f32[548] @0 (2192) ; i1 u16[560][16] @2192 (17920) ; i2 u16[544][16] @20112 (17408)
    // s3 u16[16][520] aliases i1 ; red f32[816] @0 aliases sinb+i1 head (after final barrier only)
    __shared__ __align__(16) unsigned char smem[37520];
    float*          sinb = (float*)smem;
    unsigned short* i1   = (unsigned short*)(smem + 2192);
    unsigned short* i2   = (unsigned short*)(smem + 20112);
    unsigned short* s3   = i1;

    int tid  = threadIdx.x;
    int bs   = blockIdx.x;
    int G    = blockIdx.y;
    int wv   = tid >> 6;
    int lane = tid & 63;
    int lm   = lane & 15;
    int lg   = lane >> 4;

    const bf16x8 W2a = *(const bf16x8*)(wfS +         lm * 32 + 8 * lg);
    const bf16x8 W2b = *(const bf16x8*)(wfS + 512  +  lm * 32 + 8 * lg);
    const bf16x8 W3a = *(const bf16x8*)(wfS + 1024 +  lm * 32 + 8 * lg);
    const bf16x8 W3b = *(const bf16x8*)(wfS + 1536 +  lm * 32 + 8 * lg);
    f32x4 c2v, c3v;
#pragma unroll
    for (int r = 0; r < 4; ++r) {
        c2v[r] = b2[4 * lg + r];
        c3v[r] = b3[lm];          // transposed conv3: C col = channel = lm
    }

    const float* seq = stim + (size_t)bs * T_;
    int b16 = (bs >> 3) * 16;

    // ---- hoisted per-lane swizzled bases (SWZ8 invariant under +64-row steps) ----
    int t0   = wv * 16 + lm;
    int ra2 = t0 + 3 * (lg >> 1);
    const unsigned short* pa2 = i1 + ra2 * 16 + (((lg & 1) << 3) ^ SWZ8(ra2));
    const unsigned short* pb2 = i1 + (ra2 + 6) * 16 + (((lg & 1) << 3) ^ SWZ8(ra2 + 6));
    unsigned short* pw2 = i2 + t0 * 16 + ((((lg >> 1) << 3) ^ SWZ8(t0)) + (lg & 1) * 4);
    int ra3 = t0 + 9 * (lg >> 1);
    const unsigned short* pa3 = i2 + ra3 * 16 + (((lg & 1) << 3) ^ SWZ8(ra3));
    const unsigned short* pb3 = i2 + (ra3 + 18) * 16 + (((lg & 1) << 3) ^ SWZ8(ra3 + 18));
    unsigned short* ps3 = s3 + lm * 520 + wv * 16 + 4 * lg;
    const unsigned short* pd  = s3 + lm * 520 + wv * 128 + lg * 8;
    const unsigned short* xrow = x3b + (size_t)(b16 + lm) * T3P;

    f32x4 dacc;
#pragma unroll
    for (int r = 0; r < 4; ++r) dacc[r] = 0.f;
    float nstc = 0.f;
    uint4 bq[4];

    // ---- preload chunk 0 sinb into regs ----
    int c0 = (G * 4) * 512;
    int n_in = min(512, T3_ - c0) + 26;
    float r0 = seq[c0 + tid];
    float r1 = seq[c0 + tid + 256];
    float r2 = (tid + 512 < n_in) ? seq[c0 + tid + 512] : 0.f;

    for (int cc = 0; cc < 4; ++cc) {
        c0 = (G * 4 + cc) * 512;
        int Lv = min(512, T3_ - c0);
        int n1 = Lv + 24;
        n_in = Lv + 26;

        // ---- phase X: dot(prev chunk) from s3 + bq(prev); write sinb(cc) ----
        if (cc > 0) {
#pragma unroll
            for (int kk = 0; kk < 4; ++kk) {
                bf16x8 Af = *(const bf16x8*)(pd + 32 * kk);
                dacc = __builtin_amdgcn_mfma_f32_16x16x32_bf16(Af, as_bf(bq[kk]), dacc, 0, 0, 0);
            }
        }
        sinb[tid] = r0;
        sinb[tid + 256] = r1;
        if (tid + 512 < n_in) sinb[tid + 512] = r2;
        __syncthreads();

        // ---- conv1 phase: issue bq(cc) + next-sinb global loads; zero i1 tail; scalar conv1 ----
#pragma unroll
        for (int kk = 0; kk < 4; ++kk) {
            int tg = c0 + wv * 128 + kk * 32 + lg * 8;
            int tc = (tg > 8160) ? 0 : tg;
            bq[kk] = *(const uint4*)(xrow + tc);
        }
        if (cc < 3) {
            int c0n = c0 + 512;
            int n_in_n = min(512, T3_ - c0n) + 26;
            r0 = seq[c0n + tid];
            r1 = seq[c0n + tid + 256];
            r2 = (tid + 512 < n_in_n) ? seq[c0n + tid + 512] : 0.f;
        }
        for (int z = tid; z < (560 - n1) * 8; z += 256)
            ((unsigned int*)(i1 + n1 * 16))[z] = 0;
#pragma unroll
        for (int k = 0; k < 3; ++k) {
            int v = tid + 256 * k;
            if (v < n1) {
                float s0 = sinb[v], s1 = sinb[v + 1], s2 = sinb[v + 2];
                float a[16];
#pragma unroll
                for (int co = 0; co < 16; ++co)
                    a[co] = fmaxf(b1[co] + s0 * w1[co * 3] + s1 * w1[co * 3 + 1] + s2 * w1[co * 3 + 2], 0.f);
                uint4 p0 = { pk2(a[0], a[1]),   pk2(a[2], a[3]),
                             pk2(a[4], a[5]),   pk2(a[6], a[7]) };
                uint4 p1 = { pk2(a[8], a[9]),   pk2(a[10], a[11]),
                             pk2(a[12], a[13]), pk2(a[14], a[15]) };
                int sw = SWZ8(v);
                *(uint4*)(i1 + v * 16 + sw)       = p0;
                *(uint4*)(i1 + v * 16 + (8 - sw)) = p1;
            }
        }
        __syncthreads();

        // ---- conv2 d=3 ----
#pragma unroll
        for (int k = 0; k < 9; ++k) {
            if (k == 8 && wv >= 2) break;
            bf16x8 Ba = *(const bf16x8*)(pa2 + 1024 * k);
            bf16x8 Bb = *(const bf16x8*)(pb2 + 1024 * k);
            f32x4 acc = c2v;
            acc = __builtin_amdgcn_mfma_f32_16x16x32_bf16(W2a, Ba, acc, 0, 0, 0);
            acc = __builtin_amdgcn_mfma_f32_16x16x32_bf16(W2b, Bb, acc, 0, 0, 0);
            uint2 pq = { pk2(fmaxf(acc[0], 0.f), fmaxf(acc[1], 0.f)),
                         pk2(fmaxf(acc[2], 0.f), fmaxf(acc[3], 0.f)) };
            *(uint2*)(pw2 + 1024 * k) = pq;
        }
        __syncthreads();

        // ---- conv3 d=9 transposed -> s3 + norm ----
#pragma unroll
        for (int k = 0; k < 8; ++k) {
            bf16x8 Aa = *(const bf16x8*)(pa3 + 1024 * k);
            bf16x8 Ab = *(const bf16x8*)(pb3 + 1024 * k);
            f32x4 acc = c3v;
            acc = __builtin_amdgcn_mfma_f32_16x16x32_bf16(Aa, W3a, acc, 0, 0, 0);
            acc = __builtin_amdgcn_mfma_f32_16x16x32_bf16(Ab, W3b, acc, 0, 0, 0);
            int u4 = wv * 16 + 4 * lg + 64 * k;
            float v[4];
#pragma unroll
            for (int r = 0; r < 4; ++r) {
                float x = ((u4 + r) < Lv) ? fmaxf(acc[r], 0.f) : 0.f;
                v[r] = x;
                nstc += x * x;
            }
            uint2 pq = { pk2(v[0], v[1]), pk2(v[2], v[3]) };
            *(uint2*)(ps3 + 64 * k) = pq;
        }
        __syncthreads();
    }

    // ---- final dot (chunk 3) ----
#pragma unroll
    for (int kk = 0; kk < 4; ++kk) {
        bf16x8 Af = *(const bf16x8*)(pd + 32 * kk);
        dacc = __builtin_amdgcn_mfma_f32_16x16x32_bf16(Af, as_bf(bq[kk]), dacc, 0, 0, 0);
    }
    __syncthreads();   // all dot reads of s3 done before red (aliases smem head) is written

    // ---- cross-wave reduction in LDS ----
    nstc += __shfl_xor(nstc, 16);
    nstc += __shfl_xor(nstc, 32);
    float* red  = (float*)smem;            // 768 f32 = 3072B
    float* redn = (float*)(smem + 3072);   // 48 f32
    if (wv > 0) {
        *(f32x4*)(red + ((wv - 1) * 64 + lane) * 4) = dacc;
        if (lg == 0) redn[(wv - 1) * 16 + lm] = nstc;
    }
    __syncthreads();
    if (wv == 0) {
#pragma unroll
        for (int w = 0; w < 3; ++w) {
            f32x4 o = *(const f32x4*)(red + (w * 64 + lane) * 4);
#pragma unroll
            for (int r = 0; r < 4; ++r) dacc[r] += o[r];
        }
        int ob = bs * 4 + G;
        *(f32x4*)(dotp + (size_t)ob * 256 + lane * 4) = dacc;
        if (lg == 0)
            nstp[(size_t)ob * 16 + lm] = nstc + redn[lm] + redn[16 + lm] + redn[32 + lm];
    }
}

// =========== K5: reduce partials, cosine, linear head ===========
__global__ __launch_bounds__(256) void k_head(const float* __restrict__ dotp,
                                              const float* __restrict__ nstp,
                                              const float* __restrict__ nxp,
                                              const float* __restrict__ wlin,
                                              const float* __restrict__ blin,
                                              float* __restrict__ out) {
    int bs = blockIdx.x, tid = threadIdx.x;
    int b = bs >> 3;
    __shared__ float nxv[16];
    if (tid < 16) {
        float s = 0.f;
#pragma unroll
        for (int ch = 0; ch < 32; ++ch) s += nxp[((size_t)b * 16 + tid) * 32 + ch];
        nxv[tid] = fmaxf(sqrtf(s), EPS_);
    }
    __syncthreads();
    int i = 4 * (tid >> 6) + (tid & 3);
    int j = (tid >> 2) & 15;
    float dot = 0.f, ss = 0.f;
#pragma unroll
    for (int gw = 0; gw < 4; ++gw) {
        dot += dotp[(size_t)(bs * 4 + gw) * 256 + tid];
        ss  += nstp[(size_t)(bs * 4 + gw) * 16 + i];
    }
    float nstv = fmaxf(sqrtf(ss), EPS_);
    float val = dot / (nstv * nxv[j]) * wlin[i * 16 + j];
#pragma unroll
    for (int m = 32; m > 0; m >>= 1) val += __shfl_down(val, m, 64);
    __shared__ float rd[4];
    if ((tid & 63) == 0) rd[tid >> 6] = val;
    __syncthreads();
    if (tid == 0) out[bs] = rd[0] + rd[1] + rd[2] + rd[3] + blin[0];
}

extern "C" void kernel_launch(void* const* d_in, const int* in_sizes, int n_in,
                              void* d_out, int out_size, void* d_ws, size_t ws_size,
                              hipStream_t stream) {
    const float* eeg   = (const float*)d_in[0];
    const float* stim  = (const float*)d_in[1];
    const float* w_eeg = (const float*)d_in[2];
    const float* b_eeg = (const float*)d_in[3];
    const float* w_e1  = (const float*)d_in[4];
    const float* b_e1  = (const float*)d_in[5];
    const float* w_e2  = (const float*)d_in[6];
    const float* b_e2  = (const float*)d_in[7];
    const float* w_e3  = (const float*)d_in[8];
    const float* b_e3  = (const float*)d_in[9];
    const float* w_s1  = (const float*)d_in[10];
    const float* b_s1  = (const float*)d_in[11];
    const float* w_s2  = (const float*)d_in[12];
    const float* b_s2  = (const float*)d_in[13];
    const float* w_s3  = (const float*)d_in[14];
    const float* b_s3  = (const float*)d_in[15];
    const float* w_lin = (const float*)d_in[16];
    const float* b_lin = (const float*)d_in[17];

    unsigned char* ws = (unsigned char*)d_ws;
    unsigned short* x3b  = (unsigned short*)ws;                 // 16,728,064 B
    float*          nxp  = (float*)(ws + 16728064);             // 131,072 B
    float*          dotp = (float*)(ws + 16859136);             // 2,097,152 B
    float*          nstp = (float*)(ws + 25247744);             // 131,072 B
    unsigned short* x0b  = (unsigned short*)(ws + 25772032);    // 8,388,608 B
    unsigned short* wfE  = (unsigned short*)(ws + 34160640);    // 5,120 B
    unsigned short* wfS  = (unsigned short*)(ws + 34165760);    // 4,096 B
    float*          out  = (float*)d_out;

    k_eeg1x1<<<(B_ * T_) / 256, 256, 0, stream>>>(eeg, w_eeg, b_eeg, x0b,
                                                  w_e1, w_e2, w_e3, w_s2, w_s3, wfE, wfS);
    k_estack<<<dim3(32, B_), 256, 0, stream>>>(x0b, b_e1, b_e2, b_e3, wfE, x3b, nxp);
    k_stim<<<dim3(B_ * S_, 4), 256, 0, stream>>>(stim, w_s1, b_s1, b_s2, b_s3,
                                                 wfS, x3b, dotp, nstp);
    k_head<<<B_ * S_, 256, 0, stream>>>(dotp, nstp, nxp, w_lin, b_lin, out);
}